// Round 4
// baseline (690.588 us; speedup 1.0000x reference)
//
#include <hip/hip_runtime.h>
#include <stdint.h>

// ---------------------------------------------------------------------------
// Ternary 3x3 conv block via i8 MFMA implicit GEMM.
//
// Activations: NHWC i8 ternary {-1,0,+1}, padded [64][58][58][256], halo = 0.
// Weights pre-packed in MFMA B-fragment order:
//   Bpk[nfrag(16)][unit(36)][lane(64)][16B], unit = tap*4 + cich (k-chunk).
// mconv block (round-3 reshape): M=64 (1 out row, 56 valid + 8 pad) x N=256 x
//   K=2304, 8 waves (N-split 32 each): acc[4][2] = 32 AGPRs, no B-dbuf,
//   __launch_bounds__(512,6) -> target <=85 regs = 6 waves/SIMD.
//   3 input rows staged in LDS (49.5 KB incl tail pad) -> 3 blocks/CU.
//   Rationale (round-2 counters): 2 phase-locked blocks/CU ran staging ->
//   K-loop -> epilogue fully serial (MFMA 41k + LDS 40k + HBM 45k cy/round
//   ~= 113k wall); 3 blocks x 14 rounds decorrelate phases so epilogue HBM
//   overlaps other blocks' K-loops. 12.5% MFMA pad waste accepted.
//   C/D: col=lane&15, row=(lane>>4)*4+reg.
// ---------------------------------------------------------------------------

#define NB 64
#define C  256
#define H  56
#define W  56
#define HP 58
#define PPIX 272                 // padded bytes per pixel in LDS (17*16)
#define SLOT (HP * PPIX)         // bytes per LDS row slot
#define OST 272                  // stage-1 transpose row stride (256+16)

typedef int v4i __attribute__((ext_vector_type(4)));

// ---------------- pack input: NCHW fp32 -> padded NHWC ternary i8 ----------
__global__ __launch_bounds__(256)
void pack_x_kernel(const float* __restrict__ x, int8_t* __restrict__ Aq) {
    const int h = blockIdx.x, n = blockIdx.y;
    const int w  = threadIdx.x & 63;   // 0..55 valid
    const int cq = threadIdx.x >> 6;   // 64-channel group

    __shared__ int8_t st[56 * OST];    // [w][c] ternary bytes, padded stride

    const float* xp = x + (((size_t)n * C + cq * 64) * H + h) * W + w;
#pragma unroll
    for (int i = 0; i < 16; ++i) {     // 4 channels per iter -> one u32 store
        uint32_t u = 0;
#pragma unroll
        for (int b = 0; b < 4; ++b) {
            float v = (w < 56) ? xp[(size_t)(i * 4 + b) * (H * W)] : 0.0f;
            uint32_t t = (v < 0.0f) ? 0xFFu : ((v != 0.0f) ? 1u : 0u);
            u |= t << (8 * b);
        }
        if (w < 56)
            *(uint32_t*)(st + w * OST + cq * 64 + i * 4) = u;
    }
    __syncthreads();
    // coalesced out: 56 pixels x 256 B contiguous at (h+1, 1)
    int8_t* dst = Aq + (((size_t)n * HP + h + 1) * HP + 1) * C;
    for (int idx = threadIdx.x; idx < 56 * 16; idx += 256) {
        int pix = idx >> 4, c16 = idx & 15;
        *(v4i*)(dst + (size_t)pix * C + c16 * 16) =
            *(const v4i*)(st + pix * OST + c16 * 16);
    }
}

// ---------------- pack weights into B-fragment order -----------------------
__global__ __launch_bounds__(64)
void pack_w_kernel(const float* __restrict__ wa, const float* __restrict__ wb,
                   int8_t* __restrict__ B1, int8_t* __restrict__ B2) {
    const int kstep = blockIdx.x;   // 0..35 (= tap*4 + cich)
    const int nfrag = blockIdx.y;   // 0..15
    const float* wsrc = blockIdx.z ? wb : wa;
    int8_t* dst       = blockIdx.z ? B2 : B1;
    const int lane = threadIdx.x, quad = lane >> 4, l16 = lane & 15;
    const int co = nfrag * 16 + l16;
    uint32_t pk[4];
#pragma unroll
    for (int d = 0; d < 4; ++d) {
        uint32_t u = 0;
#pragma unroll
        for (int bb = 0; bb < 4; ++bb) {
            int k = kstep * 64 + quad * 16 + d * 4 + bb;
            int tap = k >> 8, ci = k & 255;
            float v = wsrc[((size_t)co * C + ci) * 9 + tap];
            uint32_t t = (v < 0.0f) ? 0xFFu : ((v != 0.0f) ? 1u : 0u);
            u |= t << (8 * bb);
        }
        pk[d] = u;
    }
    uint4 st; st.x = pk[0]; st.y = pk[1]; st.z = pk[2]; st.w = pk[3];
    *(uint4*)(dst + ((size_t)(nfrag * 36 + kstep) * 64 + lane) * 16) = st;
}

// ---------------- zero halos of both padded activation buffers -------------
__global__ __launch_bounds__(256)
void halo_zero_kernel(int8_t* __restrict__ Aq, int8_t* __restrict__ Bq) {
    const int n = blockIdx.x;
    int8_t* buf = blockIdx.y ? Bq : Aq;
    const v4i z = (v4i){0, 0, 0, 0};
    for (int idx = threadIdx.x; idx < 228 * 16; idx += 256) {
        int px = idx >> 4, c16 = idx & 15;
        int row, col;
        if (px < 58)       { row = 0;  col = px; }
        else if (px < 116) { row = 57; col = px - 58; }
        else { int i = px - 116; row = 1 + (i >> 1); col = (i & 1) * 57; }
        *(v4i*)(buf + (((size_t)n * HP + row) * HP + col) * C + c16 * 16) = z;
    }
}

// ---------------- BN constants (match prior absmax-0 double path) ----------
__global__ __launch_bounds__(256)
void bn_prep_kernel(const float* g1, const float* b1, const float* m1, const float* v1,
                    const float* g2, const float* b2, const float* m2, const float* v2,
                    float* __restrict__ sc, float* __restrict__ sh) {
    const int co = threadIdx.x;
    const float* g = blockIdx.x ? g2 : g1;
    const float* b = blockIdx.x ? b2 : b1;
    const float* m = blockIdx.x ? m2 : m1;
    const float* v = blockIdx.x ? v2 : v1;
    double scd = (double)g[co] / sqrt((double)v[co] + 1e-5);
    sc[blockIdx.x * C + co] = (float)scd;
    sh[blockIdx.x * C + co] = (float)((double)b[co] - (double)m[co] * scd);
}

// ---------------- the conv kernels -----------------------------------------
// STAGE 1: GEMM -> BN -> ternarize -> LDS transpose -> coalesced NHWC i8.
// STAGE 2: GEMM -> BN -> +residual -> clip -> fp32 NCHW (float4).
// 512 threads = 8 waves; wave wv owns nfrags {wv*2, wv*2+1} (N-cols wv*32..+31).
// Block = 1 output row (oh = blockIdx.x), M=64 (m 56..63 are pad, discarded).
template <int STAGE>
__global__ __launch_bounds__(512, 6)
void mconv_kernel(const int8_t* __restrict__ Aq, const int8_t* __restrict__ Bpk,
                  const float* __restrict__ scp, const float* __restrict__ shp,
                  const float* __restrict__ resid,
                  int8_t* __restrict__ Bout, float* __restrict__ out) {
    const int oh = blockIdx.x;   // output row 0..55
    const int n  = blockIdx.y;
    const int tid = threadIdx.x;
    const int wv = tid >> 6, lane = tid & 63, quad = lane >> 4, l16 = lane & 15;

    // 3 staged rows + tail pad so pad-pixel reads (m+c up to 65) stay in-bounds
    __shared__ int8_t lds[3 * SLOT + 8 * PPIX];   // 49504 B -> 3 blocks/CU

    // stage input rows oh .. oh+2 (padded coords; row d -> d*SLOT)
    const int8_t* gA = Aq + ((size_t)n * HP + oh) * HP * C;
    for (int idx = tid; idx < 3 * HP * 16; idx += 512) {
        int pix = idx >> 4, c16 = idx & 15;        // pix = d*HP + col
        *(v4i*)(lds + pix * PPIX + c16 * 16) =
            *(const v4i*)(gA + (size_t)pix * C + c16 * 16);
    }
    __syncthreads();

    // per-lane A bases: pixel w = f*16 + l16 (pad pixels >=56 read garbage,
    // results discarded)
    int abase[4];
#pragma unroll
    for (int f = 0; f < 4; ++f)
        abase[f] = (f * 16 + l16) * PPIX + quad * 16;

    // B fragment pointers: wave wv owns nfrags wv*2, wv*2+1
    const int8_t* bq0 = Bpk + (size_t)((wv * 2 + 0) * 36) * 1024 + lane * 16;
    const int8_t* bq1 = Bpk + (size_t)((wv * 2 + 1) * 36) * 1024 + lane * 16;

    v4i acc[4][2];
#pragma unroll
    for (int f = 0; f < 4; ++f)
#pragma unroll
        for (int nf = 0; nf < 2; ++nf) acc[f][nf] = (v4i){0, 0, 0, 0};

#pragma unroll 1
    for (int t = 0; t < 9; ++t) {
        const int r = (t >= 6) ? 2 : ((t >= 3) ? 1 : 0);
        const int c = t - 3 * r;
        const int au = r * SLOT + c * PPIX;
#pragma unroll
        for (int ci = 0; ci < 4; ++ci) {
            v4i b0 = *(const v4i*)(bq0 + ci * 1024);
            v4i b1 = *(const v4i*)(bq1 + ci * 1024);
            v4i afr[4];
#pragma unroll
            for (int f = 0; f < 4; ++f)
                afr[f] = *(const v4i*)(lds + abase[f] + au + ci * 64);
            __builtin_amdgcn_s_setprio(1);
#pragma unroll
            for (int f = 0; f < 4; ++f) {
                acc[f][0] = __builtin_amdgcn_mfma_i32_16x16x64_i8(
                    afr[f], b0, acc[f][0], 0, 0, 0);
                acc[f][1] = __builtin_amdgcn_mfma_i32_16x16x64_i8(
                    afr[f], b1, acc[f][1], 0, 0, 0);
            }
            __builtin_amdgcn_s_setprio(0);
        }
        bq0 += 4096;
        bq1 += 4096;
    }

    // ---- epilogue ----
    if (STAGE == 1) {
        __syncthreads();   // K-loop LDS dead; reuse as transpose buffer
#pragma unroll
        for (int nf = 0; nf < 2; ++nf) {
            const int co = (wv * 2 + nf) * 16 + l16;
            const float scale = scp[co], shift = shp[co];
#pragma unroll
            for (int f = 0; f < 4; ++f) {
#pragma unroll
                for (int reg = 0; reg < 4; ++reg) {
                    int mm = f * 16 + quad * 4 + reg;
                    if (mm < 56) {
                        float v = __fadd_rn(__fmul_rn((float)acc[f][nf][reg], scale), shift);
                        int8_t t8 = (v < 0.0f) ? (int8_t)-1
                                  : ((v != 0.0f) ? (int8_t)1 : (int8_t)0);
                        lds[mm * OST + co] = t8;
                    }
                }
            }
        }
        __syncthreads();
        // coalesced out: 56 pixels x 256 B at padded (oh+1, 1)
        for (int idx = tid; idx < 56 * 16; idx += 512) {
            int ww = idx >> 4, c16 = idx & 15;
            *(v4i*)(Bout + (((size_t)n * HP + oh + 1) * HP + ww + 1) * C + c16 * 16)
                = *(const v4i*)(lds + ww * OST + c16 * 16);
        }
    } else {
#pragma unroll
        for (int nf = 0; nf < 2; ++nf) {
            const int co = (wv * 2 + nf) * 16 + l16;
            const float scale = scp[co], shift = shp[co];
#pragma unroll
            for (int f = 0; f < 4; ++f) {
                int mmb = f * 16 + quad * 4;   // 4-aligned, uniform over reg
                if (mmb < 56) {
                    size_t ridx = (((size_t)n * C + co) * H + oh) * W + mmb;
                    float4 rv = *(const float4*)(resid + ridx);
                    float rr[4] = {rv.x, rv.y, rv.z, rv.w};
                    float oo[4];
#pragma unroll
                    for (int reg = 0; reg < 4; ++reg) {
                        float v = __fadd_rn(__fmul_rn((float)acc[f][nf][reg], scale), shift);
                        float o = v + rr[reg];
                        oo[reg] = fminf(1.0f, fmaxf(-1.0f, o));
                    }
                    float4 ov; ov.x = oo[0]; ov.y = oo[1]; ov.z = oo[2]; ov.w = oo[3];
                    *(float4*)(out + ridx) = ov;
                }
            }
        }
    }
}

extern "C" void kernel_launch(void* const* d_in, const int* in_sizes, int n_in,
                              void* d_out, int out_size, void* d_ws, size_t ws_size,
                              hipStream_t stream) {
    const float* x  = (const float*)d_in[0];
    const float* w1 = (const float*)d_in[1];
    const float* g1 = (const float*)d_in[2];
    const float* b1 = (const float*)d_in[3];
    const float* m1 = (const float*)d_in[4];
    const float* v1 = (const float*)d_in[5];
    const float* w2 = (const float*)d_in[6];
    const float* g2 = (const float*)d_in[7];
    const float* b2 = (const float*)d_in[8];
    const float* m2 = (const float*)d_in[9];
    const float* v2 = (const float*)d_in[10];
    float* out = (float*)d_out;

    uint8_t* ws = (uint8_t*)d_ws;
    const size_t ASZ = (size_t)NB * HP * HP * C;       // 55,083,008 B per act buffer
    const size_t WPK = (size_t)16 * 36 * 64 * 16;      // 589,824 B per packed weight
    int8_t* Aq   = (int8_t*)(ws);
    int8_t* Bq   = (int8_t*)(ws + ASZ);
    int8_t* Bpk1 = (int8_t*)(ws + 2 * ASZ);
    int8_t* Bpk2 = (int8_t*)(ws + 2 * ASZ + WPK);
    float*  scb  = (float*)(ws + 2 * ASZ + 2 * WPK);           // [2][256]
    float*  shb  = (float*)(ws + 2 * ASZ + 2 * WPK + 2048);    // [2][256]

    halo_zero_kernel<<<dim3(NB, 2), 256, 0, stream>>>(Aq, Bq);
    bn_prep_kernel<<<dim3(2), 256, 0, stream>>>(g1, b1, m1, v1, g2, b2, m2, v2,
                                                scb, shb);
    pack_w_kernel<<<dim3(36, 16, 2), 64, 0, stream>>>(w1, w2, Bpk1, Bpk2);
    pack_x_kernel<<<dim3(H, NB), 256, 0, stream>>>(x, Aq);
    mconv_kernel<1><<<dim3(H, NB), 512, 0, stream>>>(Aq, Bpk1, scb, shb,
                                                     nullptr, Bq, nullptr);
    mconv_kernel<2><<<dim3(H, NB), 512, 0, stream>>>(Bq, Bpk2, scb + C, shb + C,
                                                     x, nullptr, out);
}

// Round 5
// 595.994 us; speedup vs baseline: 1.1587x; 1.1587x over previous
//
#include <hip/hip_runtime.h>
#include <stdint.h>

// ---------------------------------------------------------------------------
// Ternary 3x3 conv block via i8 MFMA implicit GEMM.
//
// Activations: NHWC i8 ternary {-1,0,+1}, padded [64][58][58][256], halo = 0.
// Weights pre-packed in MFMA B-fragment order:
//   Bpk[nfrag(16)][unit(36)][lane(64)][16B], unit = tap*4 + cich (k-chunk).
// mconv block (round-2 shape, reverted from round-4 regression): M=112
//   (2 out rows) x N=256 x K=2304, 8 waves N-split 32 each (acc[7][2] = 56
//   AGPRs), 4 input rows in LDS (63.1 KB -> 2 blocks/CU, 4 waves/SIMD).
//   Round-4's 1-row/3-block reshape REGRESSED (165->217 us): +52MB staging
//   fetch, +14% pad MFMA, occupancy was not the binding limit.
// Round-5 change: stage-2 epilogue was a 16B-granularity NCHW scatter
//   (lane->co stride 12.5KB): 437 MB at only 2.06 TB/s pinned the wall.
//   Now: BN'd acc -> LDS transpose [co][mm] (stride 116 dw, float4 both
//   ways, ~conflict-free) -> w-contiguous resid read + out write (224-448B
//   runs), two 128-co halves (59.4 KB reusing dead K-loop LDS).
//   C/D: col=lane&15, row=(lane>>4)*4+reg.
// ---------------------------------------------------------------------------

#define NB 64
#define C  256
#define H  56
#define W  56
#define HP 58
#define PPIX 272                 // padded bytes per pixel in LDS (17*16)
#define SLOT (HP * PPIX)         // bytes per LDS row slot
#define OST 272                  // stage-1 transpose row stride (256+16)
#define FST 116                  // stage-2 transpose stride in dwords (112+4)

typedef int v4i __attribute__((ext_vector_type(4)));

// ---------------- pack input: NCHW fp32 -> padded NHWC ternary i8 ----------
__global__ __launch_bounds__(256)
void pack_x_kernel(const float* __restrict__ x, int8_t* __restrict__ Aq) {
    const int h = blockIdx.x, n = blockIdx.y;
    const int w  = threadIdx.x & 63;   // 0..55 valid
    const int cq = threadIdx.x >> 6;   // 64-channel group

    __shared__ int8_t st[56 * OST];    // [w][c] ternary bytes, padded stride

    const float* xp = x + (((size_t)n * C + cq * 64) * H + h) * W + w;
#pragma unroll
    for (int i = 0; i < 16; ++i) {     // 4 channels per iter -> one u32 store
        uint32_t u = 0;
#pragma unroll
        for (int b = 0; b < 4; ++b) {
            float v = (w < 56) ? xp[(size_t)(i * 4 + b) * (H * W)] : 0.0f;
            uint32_t t = (v < 0.0f) ? 0xFFu : ((v != 0.0f) ? 1u : 0u);
            u |= t << (8 * b);
        }
        if (w < 56)
            *(uint32_t*)(st + w * OST + cq * 64 + i * 4) = u;
    }
    __syncthreads();
    // coalesced out: 56 pixels x 256 B contiguous at (h+1, 1)
    int8_t* dst = Aq + (((size_t)n * HP + h + 1) * HP + 1) * C;
    for (int idx = threadIdx.x; idx < 56 * 16; idx += 256) {
        int pix = idx >> 4, c16 = idx & 15;
        *(v4i*)(dst + (size_t)pix * C + c16 * 16) =
            *(const v4i*)(st + pix * OST + c16 * 16);
    }
}

// ---------------- pack weights into B-fragment order -----------------------
__global__ __launch_bounds__(64)
void pack_w_kernel(const float* __restrict__ wa, const float* __restrict__ wb,
                   int8_t* __restrict__ B1, int8_t* __restrict__ B2) {
    const int kstep = blockIdx.x;   // 0..35 (= tap*4 + cich)
    const int nfrag = blockIdx.y;   // 0..15
    const float* wsrc = blockIdx.z ? wb : wa;
    int8_t* dst       = blockIdx.z ? B2 : B1;
    const int lane = threadIdx.x, quad = lane >> 4, l16 = lane & 15;
    const int co = nfrag * 16 + l16;
    uint32_t pk[4];
#pragma unroll
    for (int d = 0; d < 4; ++d) {
        uint32_t u = 0;
#pragma unroll
        for (int bb = 0; bb < 4; ++bb) {
            int k = kstep * 64 + quad * 16 + d * 4 + bb;
            int tap = k >> 8, ci = k & 255;
            float v = wsrc[((size_t)co * C + ci) * 9 + tap];
            uint32_t t = (v < 0.0f) ? 0xFFu : ((v != 0.0f) ? 1u : 0u);
            u |= t << (8 * bb);
        }
        pk[d] = u;
    }
    uint4 st; st.x = pk[0]; st.y = pk[1]; st.z = pk[2]; st.w = pk[3];
    *(uint4*)(dst + ((size_t)(nfrag * 36 + kstep) * 64 + lane) * 16) = st;
}

// ---------------- zero halos of both padded activation buffers -------------
__global__ __launch_bounds__(256)
void halo_zero_kernel(int8_t* __restrict__ Aq, int8_t* __restrict__ Bq) {
    const int n = blockIdx.x;
    int8_t* buf = blockIdx.y ? Bq : Aq;
    const v4i z = (v4i){0, 0, 0, 0};
    for (int idx = threadIdx.x; idx < 228 * 16; idx += 256) {
        int px = idx >> 4, c16 = idx & 15;
        int row, col;
        if (px < 58)       { row = 0;  col = px; }
        else if (px < 116) { row = 57; col = px - 58; }
        else { int i = px - 116; row = 1 + (i >> 1); col = (i & 1) * 57; }
        *(v4i*)(buf + (((size_t)n * HP + row) * HP + col) * C + c16 * 16) = z;
    }
}

// ---------------- BN constants (match prior absmax-0 double path) ----------
__global__ __launch_bounds__(256)
void bn_prep_kernel(const float* g1, const float* b1, const float* m1, const float* v1,
                    const float* g2, const float* b2, const float* m2, const float* v2,
                    float* __restrict__ sc, float* __restrict__ sh) {
    const int co = threadIdx.x;
    const float* g = blockIdx.x ? g2 : g1;
    const float* b = blockIdx.x ? b2 : b1;
    const float* m = blockIdx.x ? m2 : m1;
    const float* v = blockIdx.x ? v2 : v1;
    double scd = (double)g[co] / sqrt((double)v[co] + 1e-5);
    sc[blockIdx.x * C + co] = (float)scd;
    sh[blockIdx.x * C + co] = (float)((double)b[co] - (double)m[co] * scd);
}

// ---------------- the conv kernels -----------------------------------------
// STAGE 1: GEMM -> BN -> ternarize -> LDS transpose -> coalesced NHWC i8.
// STAGE 2: GEMM -> BN -> LDS transpose -> +residual -> clip -> coalesced
//          fp32 NCHW (w-contiguous float4 runs).
// 512 threads = 8 waves; wave wv owns nfrags {wv*2, wv*2+1} (N-cols wv*32..+31).
template <int STAGE>
__global__ __launch_bounds__(512, 4)
void mconv_kernel(const int8_t* __restrict__ Aq, const int8_t* __restrict__ Bpk,
                  const float* __restrict__ scp, const float* __restrict__ shp,
                  const float* __restrict__ resid,
                  int8_t* __restrict__ Bout, float* __restrict__ out) {
    const int h2 = blockIdx.x;   // output rows h2*2, h2*2+1
    const int n  = blockIdx.y;
    const int tid = threadIdx.x;
    const int wv = tid >> 6, lane = tid & 63, quad = lane >> 4, l16 = lane & 15;

    __shared__ int8_t lds[4 * SLOT];   // 63104 B

    // stage input rows h2*2 .. h2*2+3 (row d -> d*SLOT, pixel stride PPIX)
    const int8_t* gA = Aq + ((size_t)n * HP + h2 * 2) * HP * C;
    for (int idx = tid; idx < 4 * HP * 16; idx += 512) {
        int pix = idx >> 4, c16 = idx & 15;        // pix = d*HP + col
        *(v4i*)(lds + pix * PPIX + c16 * 16) =
            *(const v4i*)(gA + (size_t)pix * C + c16 * 16);
    }
    __syncthreads();

    // per-lane A bases: m = f*16 + l16 -> (hl, w)
    int abase[7];
#pragma unroll
    for (int f = 0; f < 7; ++f) {
        int mm = f * 16 + l16;
        int hl = (mm >= 56) ? 1 : 0;
        int w  = mm - 56 * hl;
        abase[f] = hl * SLOT + w * PPIX + quad * 16;
    }

    // B fragment pointers: wave wv owns nfrags wv*2, wv*2+1
    const int8_t* bq0 = Bpk + (size_t)((wv * 2 + 0) * 36) * 1024 + lane * 16;
    const int8_t* bq1 = Bpk + (size_t)((wv * 2 + 1) * 36) * 1024 + lane * 16;

    v4i bcur[2];
    bcur[0] = *(const v4i*)(bq0);
    bcur[1] = *(const v4i*)(bq1);

    v4i acc[7][2];
#pragma unroll
    for (int f = 0; f < 7; ++f)
#pragma unroll
        for (int nf = 0; nf < 2; ++nf) acc[f][nf] = (v4i){0, 0, 0, 0};

#pragma unroll 1
    for (int t = 0; t < 9; ++t) {
        const int r = (t >= 6) ? 2 : ((t >= 3) ? 1 : 0);
        const int c = t - 3 * r;
        const int au = r * SLOT + c * PPIX;
#pragma unroll
        for (int ci = 0; ci < 4; ++ci) {
            // prefetch next unit's B fragments (flat-contiguous; final
            // iteration reads 1KB past this nfrag's tail -> still inside d_ws)
            v4i bn0 = *(const v4i*)(bq0 + (ci + 1) * 1024);
            v4i bn1 = *(const v4i*)(bq1 + (ci + 1) * 1024);
            v4i afr[7];
#pragma unroll
            for (int f = 0; f < 7; ++f)
                afr[f] = *(const v4i*)(lds + abase[f] + au + ci * 64);
            __builtin_amdgcn_s_setprio(1);
#pragma unroll
            for (int f = 0; f < 7; ++f) {
                acc[f][0] = __builtin_amdgcn_mfma_i32_16x16x64_i8(
                    afr[f], bcur[0], acc[f][0], 0, 0, 0);
                acc[f][1] = __builtin_amdgcn_mfma_i32_16x16x64_i8(
                    afr[f], bcur[1], acc[f][1], 0, 0, 0);
            }
            __builtin_amdgcn_s_setprio(0);
            bcur[0] = bn0;
            bcur[1] = bn1;
        }
        bq0 += 4096;
        bq1 += 4096;
    }

    // ---- epilogue ----
    if (STAGE == 1) {
        __syncthreads();   // K-loop LDS dead; reuse as transpose buffer
#pragma unroll
        for (int nf = 0; nf < 2; ++nf) {
            const int co = (wv * 2 + nf) * 16 + l16;
            const float scale = scp[co], shift = shp[co];
#pragma unroll
            for (int f = 0; f < 7; ++f) {
#pragma unroll
                for (int reg = 0; reg < 4; ++reg) {
                    int mm = f * 16 + quad * 4 + reg;
                    float v = __fadd_rn(__fmul_rn((float)acc[f][nf][reg], scale), shift);
                    int8_t t8 = (v < 0.0f) ? (int8_t)-1
                              : ((v != 0.0f) ? (int8_t)1 : (int8_t)0);
                    lds[mm * OST + co] = t8;
                }
            }
        }
        __syncthreads();
        // coalesced out: 112 pixels x 256 B
        for (int idx = tid; idx < 112 * 16; idx += 512) {
            int mm = idx >> 4, c16 = idx & 15;
            int hl = (mm >= 56) ? 1 : 0;
            int ww = mm - 56 * hl;
            int oh = h2 * 2 + hl;
            *(v4i*)(Bout + (((size_t)n * HP + oh + 1) * HP + ww + 1) * C + c16 * 16)
                = *(const v4i*)(lds + mm * OST + c16 * 16);
        }
    } else {
        // -------- stage-2: transpose through LDS, then coalesced NCHW ------
        float* fld = (float*)lds;   // [co'(128)][FST=116 dw]: 59,392 B
#pragma unroll 1
        for (int half = 0; half < 2; ++half) {
            __syncthreads();        // K-loop A-data (or prev half) dead
            if ((wv >> 2) == half) {
#pragma unroll
                for (int nf = 0; nf < 2; ++nf) {
                    const int co = (wv * 2 + nf) * 16 + l16;
                    const int cop = co - half * 128;
                    const float scale = scp[co], shift = shp[co];
#pragma unroll
                    for (int f = 0; f < 7; ++f) {
                        float4 vv;
                        vv.x = __fadd_rn(__fmul_rn((float)acc[f][nf][0], scale), shift);
                        vv.y = __fadd_rn(__fmul_rn((float)acc[f][nf][1], scale), shift);
                        vv.z = __fadd_rn(__fmul_rn((float)acc[f][nf][2], scale), shift);
                        vv.w = __fadd_rn(__fmul_rn((float)acc[f][nf][3], scale), shift);
                        // mm = f*16 + quad*4 (+reg): 4-aligned -> one float4
                        *(float4*)(fld + cop * FST + f * 16 + quad * 4) = vv;
                    }
                }
            }
            __syncthreads();
            // 128 co x 28 float4-chunks (2 rows x 14) = 3584 = 512 x 7
            for (int idx = tid; idx < 128 * 28; idx += 512) {
                int cop = idx / 28, j = idx - cop * 28;
                int row = (j >= 14) ? 1 : 0;
                int w4  = (j - row * 14) * 4;
                int mm  = row * 56 + w4;
                int co  = half * 128 + cop;
                float4 v = *(const float4*)(fld + cop * FST + mm);
                size_t gidx = (((size_t)n * C + co) * H + h2 * 2 + row) * W + w4;
                float4 rv = *(const float4*)(resid + gidx);
                float4 ov;
                ov.x = fminf(1.0f, fmaxf(-1.0f, v.x + rv.x));
                ov.y = fminf(1.0f, fmaxf(-1.0f, v.y + rv.y));
                ov.z = fminf(1.0f, fmaxf(-1.0f, v.z + rv.z));
                ov.w = fminf(1.0f, fmaxf(-1.0f, v.w + rv.w));
                *(float4*)(out + gidx) = ov;
            }
        }
    }
}

extern "C" void kernel_launch(void* const* d_in, const int* in_sizes, int n_in,
                              void* d_out, int out_size, void* d_ws, size_t ws_size,
                              hipStream_t stream) {
    const float* x  = (const float*)d_in[0];
    const float* w1 = (const float*)d_in[1];
    const float* g1 = (const float*)d_in[2];
    const float* b1 = (const float*)d_in[3];
    const float* m1 = (const float*)d_in[4];
    const float* v1 = (const float*)d_in[5];
    const float* w2 = (const float*)d_in[6];
    const float* g2 = (const float*)d_in[7];
    const float* b2 = (const float*)d_in[8];
    const float* m2 = (const float*)d_in[9];
    const float* v2 = (const float*)d_in[10];
    float* out = (float*)d_out;

    uint8_t* ws = (uint8_t*)d_ws;
    const size_t ASZ = (size_t)NB * HP * HP * C;       // 55,083,008 B per act buffer
    const size_t WPK = (size_t)16 * 36 * 64 * 16;      // 589,824 B per packed weight
    int8_t* Aq   = (int8_t*)(ws);
    int8_t* Bq   = (int8_t*)(ws + ASZ);
    int8_t* Bpk1 = (int8_t*)(ws + 2 * ASZ);
    int8_t* Bpk2 = (int8_t*)(ws + 2 * ASZ + WPK);
    float*  scb  = (float*)(ws + 2 * ASZ + 2 * WPK);           // [2][256]
    float*  shb  = (float*)(ws + 2 * ASZ + 2 * WPK + 2048);    // [2][256]

    halo_zero_kernel<<<dim3(NB, 2), 256, 0, stream>>>(Aq, Bq);
    bn_prep_kernel<<<dim3(2), 256, 0, stream>>>(g1, b1, m1, v1, g2, b2, m2, v2,
                                                scb, shb);
    pack_w_kernel<<<dim3(36, 16, 2), 64, 0, stream>>>(w1, w2, Bpk1, Bpk2);
    pack_x_kernel<<<dim3(H, NB), 256, 0, stream>>>(x, Aq);
    mconv_kernel<1><<<dim3(28, NB), 512, 0, stream>>>(Aq, Bpk1, scb, shb,
                                                      nullptr, Bq, nullptr);
    mconv_kernel<2><<<dim3(28, NB), 512, 0, stream>>>(Bq, Bpk2, scb + C, shb + C,
                                                      x, nullptr, out);
}